// Round 12
// baseline (209.399 us; speedup 1.0000x reference)
//
#include <hip/hip_runtime.h>

#define CCH 16
#define DD 64
#define HH 96
#define WW 96
#define HW (HH*WW)
#define DHW (DD*HH*WW)   // 589824
#define CH4 (DHW/4)      // 147456
#define DCH 16           // depth outputs per block
#define NBY (DD/DCH)     // 4 depth chunks
#define KTR 1.08f        // 27 * k_harris (S unscaled by 1/27; ranking-invariant)
#define INV27C (1.f/19683.f)

typedef float v2f __attribute__((ext_vector_type(2)));

// DPP row16 shifts: thread layout is lh-fast (lh = tid & 15), so a DPP row of
// 16 lanes == one h-column; bound_ctrl=true zero-fills at row ends (filled
// sites only feed non-emitted outputs). Harris is invariant to an up/down swap
// (every term has even degree in each gradient; a swap only flips gy's sign).
__device__ __forceinline__ float dpp_up(float v) {
    return __int_as_float(__builtin_amdgcn_update_dpp(
        0, __float_as_int(v), 0x111 /*row_shr:1*/, 0xF, 0xF, true));
}
__device__ __forceinline__ float dpp_dn(float v) {
    return __int_as_float(__builtin_amdgcn_update_dpp(
        0, __float_as_int(v), 0x101 /*row_shl:1*/, 0xF, 0xF, true));
}

// R12: fully wave-autonomous depth sweep — ZERO LDS / barriers / shuffles in
// the main loop. Thread owns 2 w sites and keeps a 6-wide x window (3 v2f
// loads/slice: left pair, own pair, right pair), recomputing the 2 halo-site
// gradients locally so the product w-conv is register-internal. h-convs via
// DPP row shifts. Block 256 thr = 16 lh x 16 lcl (4 independent waves);
// grid (24,4,16): 8 h-tiles x 3 w-groups x 4 d-chunks x 16 channels.
// launch_bounds(256,8) caps VGPR at 64 (2048 thr = max occupancy either way).
__global__ __launch_bounds__(256, 8)
void harris_sum_kernel(const float* __restrict__ x, float* __restrict__ pp) {
    __shared__ float red[4];

    const int tid = threadIdx.x;
    const int lh = tid & 15, lcl = tid >> 4;     // 16 x 16
    const int bx = blockIdx.x;                   // 0..23
    const int hb = bx & 7, wg = bx >> 3;         // 8 h-tiles, 3 w-groups
    const int lc = wg * 16 + lcl;                // 0..47 global column
    const int c  = blockIdx.z;
    const int H0 = hb * 12;
    const int o0 = blockIdx.y * DCH;
    const int gh = H0 + lh - 2;
    const bool rowok = ((unsigned)gh < HH);
    const float mask  = rowok ? 1.f : 0.f;       // box zero-pads products at OOB rows
    const float maskl = (lc > 0)  ? mask : 0.f;  // halo site w0-1 (w=-1 invalid)
    const float maskr = (lc < 47) ? mask : 0.f;  // halo site w0+2 (w=96 invalid)
    const bool lok = (lc > 0), rok = (lc < 47);
    const float* xc = x + (size_t)c * DHW;
    const int roff = gh * WW + (lc << 1);

    const v2f z2 = {0.f, 0.f};
    // window: x pairs at w0-2..-1 (L), w0..+1 (C), w0+2..+3 (R), 3 slices deep
    v2f Lp, Cp, Rp, Lm, Cm, Rm, Ln, Cn, Rn;

    auto loadsl = [&](int e, v2f& L, v2f& C, v2f& R) {
        if (rowok && (unsigned)e < DD) {
            const float* s = xc + (size_t)e * HW + roff;
            C = *(const v2f*)s;                       // 8B aligned
            L = lok ? *(const v2f*)(s - 2) : z2;      // x zero-pad at w edges
            R = rok ? *(const v2f*)(s + 2) : z2;
        } else { L = z2; C = z2; R = z2; }
    };

    loadsl(o0 - 2, Lp, Cp, Rp);
    loadsl(o0 - 1, Lm, Cm, Rm);

    v2f s2m1[6], s2m2[6];
    #pragma unroll
    for (int f = 0; f < 6; ++f) { s2m1[f] = z2; s2m2[f] = z2; }
    v2f hv = z2;
    const bool emit_row = (lh >= 2) && (lh <= 13);

    #pragma unroll 3
    for (int it = 0; it < DCH + 2; ++it) {       // 18 slices -> 16 output slices
        const int e = o0 - 1 + it;
        loadsl(e + 1, Ln, Cn, Rn);

        v2f s2c[6];
        if ((unsigned)e < DD) {                  // block-uniform branch
            const v2f AL = Lp + Lm + Ln, AC = Cp + Cm + Cn, AR = Rp + Rm + Rn;
            const v2f DL = Ln - Lp,      DC = Cn - Cp,      DR = Rn - Rp;

            // pre-gradients at 4 w sites [w0-1, w0, w0+1, w0+2]
            const float Sx0 = AC.x - AL.x,            Sx1 = AC.y - AL.y;
            const float Sx2 = AR.x - AC.x,            Sx3 = AR.y - AC.y;
            const float Tx0 = AL.x + 2.f*AL.y + AC.x, Tx1 = AL.y + 2.f*AC.x + AC.y;
            const float Tx2 = AC.x + 2.f*AC.y + AR.x, Tx3 = AC.y + 2.f*AR.x + AR.y;
            const float Td0 = DL.x + DL.y + DC.x,     Td1 = DL.y + DC.x + DC.y;
            const float Td2 = DC.x + DC.y + DR.x,     Td3 = DC.y + DR.x + DR.y;

            // h-convs via DPP; masks fold the volume/edge zero-padding
            const float gxh0 = (dpp_up(Sx0) + 2.f*Sx0 + dpp_dn(Sx0)) * maskl;
            const float gyh0 = (dpp_dn(Tx0) - dpp_up(Tx0)) * maskl;
            const float gzh0 = (dpp_up(Td0) + Td0 + dpp_dn(Td0)) * maskl;
            const float gx0  = (dpp_up(Sx1) + 2.f*Sx1 + dpp_dn(Sx1)) * mask;
            const float gy0  = (dpp_dn(Tx1) - dpp_up(Tx1)) * mask;
            const float gz0  = (dpp_up(Td1) + Td1 + dpp_dn(Td1)) * mask;
            const float gx1  = (dpp_up(Sx2) + 2.f*Sx2 + dpp_dn(Sx2)) * mask;
            const float gy1  = (dpp_dn(Tx2) - dpp_up(Tx2)) * mask;
            const float gz1  = (dpp_up(Td2) + Td2 + dpp_dn(Td2)) * mask;
            const float gxh1 = (dpp_up(Sx3) + 2.f*Sx3 + dpp_dn(Sx3)) * maskr;
            const float gyh1 = (dpp_dn(Tx3) - dpp_up(Tx3)) * maskr;
            const float gzh1 = (dpp_up(Td3) + Td3 + dpp_dn(Td3)) * maskr;

            // products: own pair + halo pair, packed
            const v2f GX = {gx0, gx1},  GY = {gy0, gy1},  GZ = {gz0, gz1};
            const v2f HX = {gxh0, gxh1}, HY = {gyh0, gyh1}, HZ = {gzh0, gzh1};
            const v2f P0 = GX*GX, P1 = GY*GY, P2 = GZ*GZ;
            const v2f P3 = GX*GY, P4 = GX*GZ, P5 = GY*GZ;
            const v2f Q0 = HX*HX, Q1 = HY*HY, Q2 = HZ*HZ;
            const v2f Q3 = HX*HY, Q4 = HX*HZ, Q5 = HY*HZ;

            // w [1,1,1] on products (register-internal) + h [1,1,1] via DPP
            #define FIELD(f, P, Q)                                          \
            {   const float s_ = (P).x + (P).y;                             \
                const float R0 = (Q).x + s_, R1 = s_ + (Q).y;               \
                s2c[f].x = dpp_up(R0) + R0 + dpp_dn(R0);                    \
                s2c[f].y = dpp_up(R1) + R1 + dpp_dn(R1); }
            FIELD(0, P0, Q0) FIELD(1, P1, Q1) FIELD(2, P2, Q2)
            FIELD(3, P3, Q3) FIELD(4, P4, Q4) FIELD(5, P5, Q5)
            #undef FIELD
        } else {
            #pragma unroll
            for (int f = 0; f < 6; ++f) s2c[f] = z2;
        }

        if (e > o0 && emit_row) {   // emit output slice o = e-1 (packed math)
            const v2f sxx = s2m2[0] + s2m1[0] + s2c[0];
            const v2f syy = s2m2[1] + s2m1[1] + s2c[1];
            const v2f szz = s2m2[2] + s2m1[2] + s2c[2];
            const v2f sxy = s2m2[3] + s2m1[3] + s2c[3];
            const v2f sxz = s2m2[4] + s2m1[4] + s2c[4];
            const v2f syz = s2m2[5] + s2m1[5] + s2c[5];
            const v2f det = sxx*(syy*szz - syz*syz)
                          - sxy*(sxy*szz - syz*sxz)
                          + sxz*(sxy*syz - syy*sxz);
            const v2f tr = sxx + syy + szz;
            hv += det - KTR * (tr * tr);   // unscaled by 27^-3: ranking-invariant
        }
        #pragma unroll
        for (int f = 0; f < 6; ++f) { s2m2[f] = s2m1[f]; s2m1[f] = s2c[f]; }
        Lp = Lm; Cp = Cm; Rp = Rm;
        Lm = Ln; Cm = Cn; Rm = Rn;
    }

    float hs = hv.x + hv.y;
    // in-wave reduce -> tiny LDS -> per-block partial slot (no atomics)
    #pragma unroll
    for (int o = 32; o > 0; o >>= 1) hs += __shfl_down(hs, o, 64);
    if ((tid & 63) == 0) red[tid >> 6] = hs;
    __syncthreads();
    if (tid == 0)
        pp[c * 96 + blockIdx.y * 24 + bx] =
            (red[0] + red[1] + red[2] + red[3]) * INV27C;
}

// Sum 96 partials/channel, top-8 select (strict >: stable ties), gather copy.
__global__ __launch_bounds__(256)
void gather_topk_kernel(const float* __restrict__ x, const float* __restrict__ pp,
                        float4* __restrict__ out) {
    __shared__ float pv[CCH];
    __shared__ int sidx[8];
    const int tid = threadIdx.x;
    if (tid < CCH) {
        float s = 0.f;
        #pragma unroll
        for (int j = 0; j < 96; ++j) s += pp[tid * 96 + j];
        pv[tid] = s;   // fixed order -> deterministic across blocks
    }
    __syncthreads();
    if (tid == 0) {
        bool used[CCH];
        #pragma unroll
        for (int i = 0; i < CCH; ++i) used[i] = false;
        for (int j = 0; j < 8; ++j) {
            int best = 0; float bv = -__builtin_inff();
            for (int i = 0; i < CCH; ++i)
                if (!used[i] && pv[i] > bv) { bv = pv[i]; best = i; }
            used[best] = true;
            sidx[j] = best;
        }
    }
    __syncthreads();
    const int j   = blockIdx.y;                      // 0..7
    const int pos = blockIdx.x * 256 + tid;          // 576*256 == CH4 exact
    const int cidx = sidx[j];
    const float4* src = (const float4*)(x + (size_t)cidx * DHW);
    out[(size_t)j * CH4 + pos] = src[pos];
}

extern "C" void kernel_launch(void* const* d_in, const int* in_sizes, int n_in,
                              void* d_out, int out_size, void* d_ws, size_t ws_size,
                              hipStream_t stream) {
    const float* x = (const float*)d_in[0];
    float4* out = reinterpret_cast<float4*>(d_out);
    float* pp = (float*)d_ws;                        // 1536 per-block partials (6 KB)

    dim3 g1(24, NBY, CCH);                           // (24,4,16) = 1536 blocks
    harris_sum_kernel<<<g1, 256, 0, stream>>>(x, pp);

    dim3 g2(CH4 / 256, 8, 1);                        // (576, 8)
    gather_topk_kernel<<<g2, 256, 0, stream>>>(x, pp, out);
}